// Round 1
// 293.077 us; speedup vs baseline: 1.0138x; 1.0138x over previous
//
#include <hip/hip_runtime.h>

#define D_MODEL 1024
#define TSEQ    4096
#define BATCH   4
#define MROWS   (BATCH * TSEQ)   // 16384
#define KDIM    1024
#define NDIM    1024
#define EPSV    1e-6f

typedef __attribute__((ext_vector_type(8))) short short8;
typedef __attribute__((ext_vector_type(4))) float floatx4;

__device__ inline unsigned short f2bf(float f) {
  unsigned u = __float_as_uint(f);
  unsigned r = (u + 0x7FFFu + ((u >> 16) & 1u)) >> 16;  // RNE
  return (unsigned short)r;
}
__device__ inline float bf2f(unsigned short h) {
  return __uint_as_float(((unsigned)h) << 16);
}
__device__ inline float phi_f(float x) { return x > 0.f ? x + 1.f : __expf(x); }

// async global->LDS, 16B per lane (linear dest = wave base + lane*16)
#define GLD16(gp, lp) __builtin_amdgcn_global_load_lds( \
    (const __attribute__((address_space(1))) void*)(gp), \
    (__attribute__((address_space(3))) void*)(lp), 16, 0, 0)

// ---------------- fused prep: fp32->bf16 (x + 4 weights) + zero ksum/kvsum ----
#define NX4 4194304   // x float4 count
#define NW4 262144    // one weight float4 count
#define NZ4 2048      // ksum+kvsum float4 count

__global__ __launch_bounds__(256) void prep_kernel(
    const float* __restrict__ x,  const float* __restrict__ wq,
    const float* __restrict__ wk, const float* __restrict__ wv,
    const float* __restrict__ wg,
    unsigned short* __restrict__ xb,  unsigned short* __restrict__ wqb,
    unsigned short* __restrict__ wkb, unsigned short* __restrict__ wvb,
    unsigned short* __restrict__ wgb, float* __restrict__ zbase)
{
  long i = (long)blockIdx.x * 256 + threadIdx.x;
  const float* src; unsigned short* dst; long j = i;
  if (j < NX4) { src = x; dst = xb; }
  else {
    j -= NX4;
    if (j < NW4) { src = wq; dst = wqb; }
    else { j -= NW4;
      if (j < NW4) { src = wk; dst = wkb; }
      else { j -= NW4;
        if (j < NW4) { src = wv; dst = wvb; }
        else { j -= NW4;
          if (j < NW4) { src = wg; dst = wgb; }
          else { j -= NW4;
            if (j < NZ4) { float4 zz = {0.f,0.f,0.f,0.f}; ((float4*)zbase)[j] = zz; }
            return;
          }
        }
      }
    }
  }
  float4 f = ((const float4*)src)[j];
  ushort4 o;
  o.x = f2bf(f.x); o.y = f2bf(f.y); o.z = f2bf(f.z); o.w = f2bf(f.w);
  ((ushort4*)dst)[j] = o;
}

#define BM 128
#define BN 128
#define BK 32

// ---------------- phase 1: k/v GEMM with in-register fused reduction --------
// Pipelined 2-phase: double-buffered LDS; next K-tile's global_load_lds are
// issued BEFORE computing the current tile, so the vmcnt(0) drain implicit in
// the single per-step __syncthreads() lands after ~ds_read+MFMA cycles of the
// load latency have already elapsed. One barrier per K-step (was two).
__global__ __launch_bounds__(256, 2) void gemm_kv_kernel(
    const unsigned short* __restrict__ A,
    const unsigned short* __restrict__ Wk, const unsigned short* __restrict__ Wv,
    float* __restrict__ ksum, float* __restrict__ kvsum)
{
  const int bn = blockIdx.x;   // 0..7
  const int bm = blockIdx.y;   // 0..127

  __shared__ __align__(16) unsigned short As [2][BM * BK];
  __shared__ __align__(16) unsigned short Bks[2][BN * BK];
  __shared__ __align__(16) unsigned short Bvs[2][BN * BK];

  const int tid  = threadIdx.x;
  const int lane = tid & 63;
  const int w    = tid >> 6;          // 0..3
  const int wr   = (w >> 1) * 64;
  const int wc   = (w & 1) * 64;

  floatx4 ak[4][4], av[4][4];
#pragma unroll
  for (int i = 0; i < 4; i++)
#pragma unroll
    for (int j = 0; j < 4; j++) {
      floatx4 zz = {0.f,0.f,0.f,0.f}; ak[i][j] = zz; av[i][j] = zz;
    }

  const unsigned short* Ablk  = A  + (size_t)bm * BM * KDIM;
  const unsigned short* Bkblk = Wk + (size_t)bn * BN * KDIM;
  const unsigned short* Bvblk = Wv + (size_t)bn * BN * KDIM;

  const int la = lane & 15;
  const int lk = (lane >> 4) * 8;

  // staging geometry: 512 16B-slots per tile, 256 threads -> 2 slots each
  const int f0 = tid;         // 0..255
  const int f1 = tid + 256;   // 256..511
  const int r0 = f0 >> 2, c0 = (f0 & 3) * 8;
  const int r1 = f1 >> 2, c1 = (f1 & 3) * 8;

  auto stage = [&](int buf, int kt) {
    size_t g0 = (size_t)r0 * KDIM + kt + c0;
    size_t g1 = (size_t)r1 * KDIM + kt + c1;
    GLD16(Ablk  + g0, &As [buf][f0 * 8]); GLD16(Ablk  + g1, &As [buf][f1 * 8]);
    GLD16(Bkblk + g0, &Bks[buf][f0 * 8]); GLD16(Bkblk + g1, &Bks[buf][f1 * 8]);
    GLD16(Bvblk + g0, &Bvs[buf][f0 * 8]); GLD16(Bvblk + g1, &Bvs[buf][f1 * 8]);
  };

  auto compute = [&](int buf) {
    short8 af[4], bk[4], bv[4];
#pragma unroll
    for (int i = 0; i < 4; i++) {
      af[i] = *(const short8*)&As [buf][(wr + i * 16 + la) * BK + lk];
      bk[i] = *(const short8*)&Bks[buf][(wc + i * 16 + la) * BK + lk];
      bv[i] = *(const short8*)&Bvs[buf][(wc + i * 16 + la) * BK + lk];
    }
    __builtin_amdgcn_s_setprio(1);
#pragma unroll
    for (int i = 0; i < 4; i++)
#pragma unroll
      for (int j = 0; j < 4; j++) {
        ak[i][j] = __builtin_amdgcn_mfma_f32_16x16x32_bf16(af[i], bk[j], ak[i][j], 0, 0, 0);
        av[i][j] = __builtin_amdgcn_mfma_f32_16x16x32_bf16(af[i], bv[j], av[i][j], 0, 0, 0);
      }
    __builtin_amdgcn_s_setprio(0);
  };

  stage(0, 0);
  __syncthreads();
  // KDIM/(2*BK) = 16 double-steps; static buffer indices (no runtime cur)
  for (int kt = 0; kt < KDIM; kt += 2 * BK) {
    stage(1, kt + BK);                       // prefetch overlaps compute(0)
    compute(0);
    __syncthreads();                          // drains vmcnt -> buf1 ready
    if (kt + 2 * BK < KDIM) stage(0, kt + 2 * BK);
    compute(1);
    __syncthreads();
  }

  // ---- fused column reduction ----
  const int b = bm >> 5;              // 32 bm-blocks per batch
  float kp[4] = {0.f,0.f,0.f,0.f};
  float vp[4] = {0.f,0.f,0.f,0.f};
#pragma unroll
  for (int j = 0; j < 4; j++)
#pragma unroll
    for (int i = 0; i < 4; i++)
#pragma unroll
      for (int r = 0; r < 4; r++) {
        float kk = phi_f(ak[i][j][r]);
        kp[j] += kk;
        vp[j] += kk * av[i][j][r];
      }
  // sum over the 4 row-quads (lane>>4): xor 16, 32
#pragma unroll
  for (int j = 0; j < 4; j++) {
    kp[j] += __shfl_xor(kp[j], 16, 64); kp[j] += __shfl_xor(kp[j], 32, 64);
    vp[j] += __shfl_xor(vp[j], 16, 64); vp[j] += __shfl_xor(vp[j], 32, 64);
  }
  if (lane < 16) {
#pragma unroll
    for (int j = 0; j < 4; j++) {
      int col = bn * BN + wc + j * 16 + lane;
      atomicAdd(ksum  + (size_t)b * D_MODEL + col, kp[j]);
      atomicAdd(kvsum + (size_t)b * D_MODEL + col, vp[j]);
    }
  }
}

// ---------------- phase 2: q/g GEMM with fused finalize ---------------------
// 512 threads: waves 0-3 compute q 128x128, waves 4-7 compute g 128x128.
// Same pipelined 2-phase schedule. This kernel is 1 block/CU (184 regs/wave),
// so intra-block prefetch overlap is the only latency hiding available.
__global__ __launch_bounds__(512) void gemm_qg_kernel(
    const unsigned short* __restrict__ A,
    const unsigned short* __restrict__ Wq, const unsigned short* __restrict__ Wg,
    const float* __restrict__ x, const float* __restrict__ bg,
    const float* __restrict__ ksum, const float* __restrict__ kvsum,
    float* __restrict__ out)
{
  const int bn = blockIdx.x;   // 0..7
  const int bm = blockIdx.y;   // 0..127

  __shared__ __align__(16) unsigned short As [2][BM * BK];
  __shared__ __align__(16) unsigned short Bqs[2][BN * BK];
  __shared__ __align__(16) unsigned short Bgs[2][BN * BK];
  __shared__ float o_lds[2 * BM];     // [head_local][row_local]

  const int tid  = threadIdx.x;
  const int lane = tid & 63;
  const int w    = tid >> 6;          // 0..7
  const int is_g = w >> 2;
  const int wl   = w & 3;
  const int wr   = (wl >> 1) * 64;
  const int wc   = (wl & 1) * 64;

  floatx4 acc[4][4];
#pragma unroll
  for (int i = 0; i < 4; i++)
#pragma unroll
    for (int j = 0; j < 4; j++) { floatx4 zz = {0.f,0.f,0.f,0.f}; acc[i][j] = zz; }

  const unsigned short* Ablk  = A + (size_t)bm * BM * KDIM;
  const unsigned short* Bqblk = Wq + (size_t)bn * BN * KDIM;
  const unsigned short* Bgblk = Wg + (size_t)bn * BN * KDIM;

  const int la = lane & 15;
  const int lk = (lane >> 4) * 8;

  const int f  = tid;                 // 0..511: one 16B slot per thread per tile
  const int rr = f >> 2, cc = (f & 3) * 8;

  auto stage = [&](int buf, int kt) {
    size_t g = (size_t)rr * KDIM + kt + cc;
    GLD16(Ablk  + g, &As [buf][f * 8]);
    GLD16(Bqblk + g, &Bqs[buf][f * 8]);
    GLD16(Bgblk + g, &Bgs[buf][f * 8]);
  };

  auto compute = [&](int buf) {
    const unsigned short* Bsm = is_g ? &Bgs[buf][0] : &Bqs[buf][0];
    short8 af[4], bfg[4];
#pragma unroll
    for (int i = 0; i < 4; i++) {
      af[i]  = *(const short8*)&As[buf][(wr + i * 16 + la) * BK + lk];
      bfg[i] = *(const short8*)&Bsm[(wc + i * 16 + la) * BK + lk];
    }
    __builtin_amdgcn_s_setprio(1);
#pragma unroll
    for (int i = 0; i < 4; i++)
#pragma unroll
      for (int j = 0; j < 4; j++)
        acc[i][j] = __builtin_amdgcn_mfma_f32_16x16x32_bf16(af[i], bfg[j], acc[i][j], 0, 0, 0);
    __builtin_amdgcn_s_setprio(0);
  };

  stage(0, 0);
  __syncthreads();
  for (int kt = 0; kt < KDIM; kt += 2 * BK) {
    stage(1, kt + BK);
    compute(0);
    __syncthreads();
    if (kt + 2 * BK < KDIM) stage(0, kt + 2 * BK);
    compute(1);
    __syncthreads();
  }

  // ---- fused finalize ----
  const int b  = bm >> 5;
  const int ro = (lane >> 4) * 4;
  const int co = lane & 15;
  const int hl = wc >> 6;             // head_local (0/1): wave spans one head

  if (!is_g) {
    float kvv[4], ksv[4];
#pragma unroll
    for (int j = 0; j < 4; j++) {
      int col = bn * BN + wc + j * 16 + co;
      kvv[j] = kvsum[(size_t)b * D_MODEL + col];
      ksv[j] = ksum [(size_t)b * D_MODEL + col];
    }
#pragma unroll
    for (int i = 0; i < 4; i++)
#pragma unroll
      for (int r = 0; r < 4; r++) {
        float s = 0.f, z = 0.f;
#pragma unroll
        for (int j = 0; j < 4; j++) {
          float qq = phi_f(acc[i][j][r]);
          s += qq * kvv[j]; z += qq * ksv[j];
        }
#pragma unroll
        for (int m = 1; m < 16; m <<= 1) {  // sum cols across 16-lane group
          s += __shfl_xor(s, m, 64);
          z += __shfl_xor(z, m, 64);
        }
        if (co == 0) o_lds[hl * BM + wr + i * 16 + ro + r] = s / (z + EPSV);
      }
  }
  __syncthreads();
  if (is_g) {
    float bgv[4];
#pragma unroll
    for (int j = 0; j < 4; j++) bgv[j] = bg[bn * BN + wc + j * 16 + co];
#pragma unroll
    for (int i = 0; i < 4; i++)
#pragma unroll
      for (int r = 0; r < 4; r++) {
        int rowl = wr + i * 16 + ro + r;
        int grow = bm * BM + rowl;
        float ov = o_lds[hl * BM + rowl];
#pragma unroll
        for (int j = 0; j < 4; j++) {
          int gcol = bn * BN + wc + j * 16 + co;
          float gt = 1.f / (1.f + __expf(-(acc[i][j][r] + bgv[j])));
          float xv = x[(size_t)grow * D_MODEL + gcol];
          out[(size_t)grow * D_MODEL + gcol] = gt * ov + (1.f - gt) * xv;
        }
      }
  }
}

extern "C" void kernel_launch(void* const* d_in, const int* in_sizes, int n_in,
                              void* d_out, int out_size, void* d_ws, size_t ws_size,
                              hipStream_t stream) {
  (void)in_sizes; (void)n_in; (void)out_size; (void)ws_size;
  const float* x  = (const float*)d_in[0];
  const float* Wq = (const float*)d_in[1];
  const float* Wk = (const float*)d_in[2];
  const float* Wv = (const float*)d_in[3];
  /* d_in[4] = Wo — unused by the reference */
  const float* Wg = (const float*)d_in[5];
  const float* bg = (const float*)d_in[6];
  float* out = (float*)d_out;

  char* ws = (char*)d_ws;
  const size_t xel = (size_t)MROWS * D_MODEL;
  const size_t wel = (size_t)NDIM * KDIM;
  unsigned short* xbf = (unsigned short*)ws; ws += xel * 2;
  unsigned short* wqb = (unsigned short*)ws; ws += wel * 2;
  unsigned short* wkb = (unsigned short*)ws; ws += wel * 2;
  unsigned short* wvb = (unsigned short*)ws; ws += wel * 2;
  unsigned short* wgb = (unsigned short*)ws; ws += wel * 2;
  float* ksum  = (float*)ws; ws += (size_t)BATCH * D_MODEL * 4;  // contiguous
  float* kvsum = (float*)ws; ws += (size_t)BATCH * D_MODEL * 4;

  // 1) fused converts + zero
  const long total4 = (long)NX4 + 4L * NW4 + NZ4;
  prep_kernel<<<(int)((total4 + 255) / 256), 256, 0, stream>>>(
      x, Wq, Wk, Wv, Wg, xbf, wqb, wkb, wvb, wgb, ksum);

  // 2) phase 1: k/v with fused reduction
  dim3 g1(NDIM / BN, MROWS / BM);
  gemm_kv_kernel<<<g1, 256, 0, stream>>>(xbf, wkb, wvb, ksum, kvsum);

  // 3) phase 2: q/g with fused finalize
  dim3 g2(NDIM / BN, MROWS / BM);
  gemm_qg_kernel<<<g2, 512, 0, stream>>>(xbf, wqb, wgb, x, bg, ksum, kvsum, out);
}

// Round 2
// 278.498 us; speedup vs baseline: 1.0669x; 1.0523x over previous
//
#include <hip/hip_runtime.h>

#define D_MODEL 1024
#define TSEQ    4096
#define BATCH   4
#define MROWS   (BATCH * TSEQ)   // 16384
#define KDIM    1024
#define NDIM    1024
#define EPSV    1e-6f

typedef __attribute__((ext_vector_type(8))) short short8;
typedef __attribute__((ext_vector_type(4))) float floatx4;

__device__ inline unsigned short f2bf(float f) {
  unsigned u = __float_as_uint(f);
  unsigned r = (u + 0x7FFFu + ((u >> 16) & 1u)) >> 16;  // RNE
  return (unsigned short)r;
}
__device__ inline float phi_f(float x) { return x > 0.f ? x + 1.f : __expf(x); }

// async global->LDS, 16B per lane (linear dest = wave base + lane*16)
#define GLD16(gp, lp) __builtin_amdgcn_global_load_lds( \
    (const __attribute__((address_space(1))) void*)(gp), \
    (__attribute__((address_space(3))) void*)(lp), 16, 0, 0)

// ---------------- fused prep: fp32->bf16 (x + 4 weights) + zero ksum/kvsum ----
#define NX4 4194304   // x float4 count
#define NW4 262144    // one weight float4 count
#define NZ4 2048      // ksum+kvsum float4 count

__global__ __launch_bounds__(256) void prep_kernel(
    const float* __restrict__ x,  const float* __restrict__ wq,
    const float* __restrict__ wk, const float* __restrict__ wv,
    const float* __restrict__ wg,
    unsigned short* __restrict__ xb,  unsigned short* __restrict__ wqb,
    unsigned short* __restrict__ wkb, unsigned short* __restrict__ wvb,
    unsigned short* __restrict__ wgb, float* __restrict__ zbase)
{
  long i = (long)blockIdx.x * 256 + threadIdx.x;
  const float* src; unsigned short* dst; long j = i;
  if (j < NX4) { src = x; dst = xb; }
  else {
    j -= NX4;
    if (j < NW4) { src = wq; dst = wqb; }
    else { j -= NW4;
      if (j < NW4) { src = wk; dst = wkb; }
      else { j -= NW4;
        if (j < NW4) { src = wv; dst = wvb; }
        else { j -= NW4;
          if (j < NW4) { src = wg; dst = wgb; }
          else { j -= NW4;
            if (j < NZ4) { float4 zz = {0.f,0.f,0.f,0.f}; ((float4*)zbase)[j] = zz; }
            return;
          }
        }
      }
    }
  }
  float4 f = ((const float4*)src)[j];
  ushort4 o;
  o.x = f2bf(f.x); o.y = f2bf(f.y); o.z = f2bf(f.z); o.w = f2bf(f.w);
  ((ushort4*)dst)[j] = o;
}

// ---------------- phase-split GEMM geometry ---------------------------------
// 256(M) x 128(N) tile, BK=64, 512 threads (8 waves). 16 K-steps, 4 phases
// each. LDS rows are 128 B (exact 32-bank wrap) -> T2 XOR swizzle slot^=row&7
// (16B slots), applied as: linear global_load_lds dest + inverse-swizzled
// GLOBAL source + swizzled ds_read (rule #21). Raw s_barrier (no implicit
// vmcnt drain); one counted-wait point per K-step, ~2.5 phases after issue.
#define BM 256
#define BN 128
#define BK 64
#define NSTEP (KDIM / BK)   // 16

// staging: A tile 256x64 = 2048 16B slots (4/thread); B tiles 1024 (2/thread)

// ---------------- phase 1: k/v GEMM with in-register fused reduction --------
// Every wave computes BOTH k and v on its 128x32 sub-tile (shared A frags),
// then reduces phi(k) and phi(k)*v over its rows and atomicAdds. 16 MFMA per
// phase (2 rowpairs x 2 cols x 2 kk x 2 matrices).
__global__ __launch_bounds__(512, 1) void gemm_kv_kernel(
    const unsigned short* __restrict__ A,
    const unsigned short* __restrict__ Wk, const unsigned short* __restrict__ Wv,
    float* __restrict__ ksum, float* __restrict__ kvsum)
{
  __shared__ __align__(16) unsigned short As0[BM * BK], As1[BM * BK];   // 64 KB
  __shared__ __align__(16) unsigned short Bk0[BN * BK], Bk1[BN * BK];   // 32 KB
  __shared__ __align__(16) unsigned short Bv0[BN * BK], Bv1[BN * BK];   // 32 KB

  // T1 bijective XCD swizzle: 512 blocks = 8 xcd * 64
  const int bid = blockIdx.x;
  const int sw  = (bid & 7) * 64 + (bid >> 3);
  const int bn  = sw & 7;    // 0..7
  const int bm  = sw >> 3;   // 0..63

  const int tid  = threadIdx.x;
  const int lane = tid & 63;
  const int w    = tid >> 6;           // 0..7
  const int wr   = (w >> 2) * 128;     // 2 row groups
  const int wc   = (w & 3) * 32;       // 4 col groups
  const int la   = lane & 15;
  const int l4   = lane >> 4;

  floatx4 ak[8][2], av[8][2];
#pragma unroll
  for (int i = 0; i < 8; i++)
#pragma unroll
    for (int j = 0; j < 2; j++) {
      floatx4 zz = {0.f,0.f,0.f,0.f}; ak[i][j] = zz; av[i][j] = zz;
    }

  const unsigned short* Ablk = A  + (size_t)bm * BM * KDIM;
  const unsigned short* Bkb  = Wk + (size_t)bn * BN * KDIM;
  const unsigned short* Bvb  = Wv + (size_t)bn * BN * KDIM;

  // stage half: half 0 -> A slots {tid, tid+512} + B slots {tid}
  //             half 1 -> A slots {tid+1024, tid+1536} + B slots {tid+512}
  auto stage_half = [&](unsigned short* Aw, unsigned short* Bkw, unsigned short* Bvw,
                        int kt, int half) {
#pragma unroll
    for (int j = 0; j < 2; ++j) {
      int s = tid + (half * 2 + j) * 512;
      int row = s >> 3, sl = s & 7;
      size_t g = (size_t)row * KDIM + kt + ((sl ^ (row & 7)) << 3);
      GLD16(Ablk + g, Aw + (size_t)s * 8);
    }
    {
      int s = tid + half * 512;
      int row = s >> 3, sl = s & 7;
      size_t g = (size_t)row * KDIM + kt + ((sl ^ (row & 7)) << 3);
      GLD16(Bkb + g, Bkw + (size_t)s * 8);
      GLD16(Bvb + g, Bvw + (size_t)s * 8);
    }
  };

  // one K-step: read Ar/Bkr/Bvr, prefetch kt_next into Aw/Bkw/Bvw
  auto kstep = [&](const unsigned short* Ar, const unsigned short* Bkr,
                   const unsigned short* Bvr,
                   unsigned short* Aw, unsigned short* Bkw, unsigned short* Bvw,
                   int ktn, bool pre) {
    short8 bkf[2][2], bvf[2][2];
#pragma unroll
    for (int p = 0; p < 4; ++p) {
      short8 af[2][2];
#pragma unroll
      for (int rp = 0; rp < 2; ++rp)
#pragma unroll
        for (int kk = 0; kk < 2; ++kk) {
          int row  = wr + (2 * p + rp) * 16 + la;
          int slot = kk * 4 + l4;
          af[rp][kk] = *(const short8*)(Ar + row * BK + ((slot ^ (row & 7)) << 3));
        }
      if (p == 0) {
#pragma unroll
        for (int j = 0; j < 2; ++j)
#pragma unroll
          for (int kk = 0; kk < 2; ++kk) {
            int row  = wc + j * 16 + la;
            int slot = kk * 4 + l4;
            int off  = row * BK + ((slot ^ (row & 7)) << 3);
            bkf[j][kk] = *(const short8*)(Bkr + off);
            bvf[j][kk] = *(const short8*)(Bvr + off);
          }
      }
      if (p == 0 && pre) stage_half(Aw, Bkw, Bvw, ktn, 0);
      if (p == 1 && pre) stage_half(Aw, Bkw, Bvw, ktn, 1);
      __builtin_amdgcn_s_barrier();
      __builtin_amdgcn_s_setprio(1);
#pragma unroll
      for (int rp = 0; rp < 2; ++rp)
#pragma unroll
        for (int j = 0; j < 2; ++j)
#pragma unroll
          for (int kk = 0; kk < 2; ++kk) {
            ak[2*p+rp][j] = __builtin_amdgcn_mfma_f32_16x16x32_bf16(
                af[rp][kk], bkf[j][kk], ak[2*p+rp][j], 0, 0, 0);
            av[2*p+rp][j] = __builtin_amdgcn_mfma_f32_16x16x32_bf16(
                af[rp][kk], bvf[j][kk], av[2*p+rp][j], 0, 0, 0);
          }
      __builtin_amdgcn_s_setprio(0);
      if (p == 3) asm volatile("s_waitcnt vmcnt(0)" ::: "memory");
      __builtin_amdgcn_s_barrier();
    }
  };

  stage_half(As0, Bk0, Bv0, 0, 0);
  stage_half(As0, Bk0, Bv0, 0, 1);
  asm volatile("s_waitcnt vmcnt(0)" ::: "memory");
  __builtin_amdgcn_s_barrier();

  for (int st2 = 0; st2 < NSTEP; st2 += 2) {
    kstep(As0, Bk0, Bv0, As1, Bk1, Bv1, (st2 + 1) * BK, true);
    kstep(As1, Bk1, Bv1, As0, Bk0, Bv0, (st2 + 2) * BK, st2 + 2 < NSTEP);
  }

  // ---- fused column reduction ----
  const int b = bm >> 4;               // 16 bm-blocks per batch (256 rows each)
  float kp[2] = {0.f, 0.f};
  float vp[2] = {0.f, 0.f};
#pragma unroll
  for (int j = 0; j < 2; j++)
#pragma unroll
    for (int mi = 0; mi < 8; mi++)
#pragma unroll
      for (int r = 0; r < 4; r++) {
        float kk = phi_f(ak[mi][j][r]);
        kp[j] += kk;
        vp[j] += kk * av[mi][j][r];
      }
#pragma unroll
  for (int j = 0; j < 2; j++) {
    kp[j] += __shfl_xor(kp[j], 16, 64); kp[j] += __shfl_xor(kp[j], 32, 64);
    vp[j] += __shfl_xor(vp[j], 16, 64); vp[j] += __shfl_xor(vp[j], 32, 64);
  }
  if (lane < 16) {
#pragma unroll
    for (int j = 0; j < 2; j++) {
      int col = bn * BN + wc + j * 16 + lane;
      atomicAdd(ksum  + (size_t)b * D_MODEL + col, kp[j]);
      atomicAdd(kvsum + (size_t)b * D_MODEL + col, vp[j]);
    }
  }
}

// ---------------- phase 2: q/g GEMM with fused finalize ---------------------
// Waves 0-3 compute q on 256x128 (128x64 each), waves 4-7 compute g. A wave's
// 64 cols = exactly one head -> s,z reduce fully in-wave. 16 MFMA per phase.
__global__ __launch_bounds__(512, 1) void gemm_qg_kernel(
    const unsigned short* __restrict__ A,
    const unsigned short* __restrict__ Wq, const unsigned short* __restrict__ Wg,
    const float* __restrict__ x, const float* __restrict__ bg,
    const float* __restrict__ ksum, const float* __restrict__ kvsum,
    float* __restrict__ out)
{
  __shared__ __align__(16) unsigned short As0[BM * BK], As1[BM * BK];
  __shared__ __align__(16) unsigned short Bq0[BN * BK], Bq1[BN * BK];
  __shared__ __align__(16) unsigned short Bg0[BN * BK], Bg1[BN * BK];
  __shared__ float o_lds[2 * BM];      // [head_local][row_local]

  const int bid = blockIdx.x;
  const int sw  = (bid & 7) * 64 + (bid >> 3);
  const int bn  = sw & 7;
  const int bm  = sw >> 3;

  const int tid  = threadIdx.x;
  const int lane = tid & 63;
  const int w    = tid >> 6;           // 0..7
  const int is_g = w >> 2;
  const int wl   = w & 3;
  const int wr   = (wl >> 1) * 128;
  const int wc   = (wl & 1) * 64;
  const int la   = lane & 15;
  const int l4   = lane >> 4;

  floatx4 acc[8][4];
#pragma unroll
  for (int i = 0; i < 8; i++)
#pragma unroll
    for (int j = 0; j < 4; j++) { floatx4 zz = {0.f,0.f,0.f,0.f}; acc[i][j] = zz; }

  const unsigned short* Ablk = A  + (size_t)bm * BM * KDIM;
  const unsigned short* Bqb  = Wq + (size_t)bn * BN * KDIM;
  const unsigned short* Bgb  = Wg + (size_t)bn * BN * KDIM;

  auto stage_half = [&](unsigned short* Aw, unsigned short* Bqw, unsigned short* Bgw,
                        int kt, int half) {
#pragma unroll
    for (int j = 0; j < 2; ++j) {
      int s = tid + (half * 2 + j) * 512;
      int row = s >> 3, sl = s & 7;
      size_t g = (size_t)row * KDIM + kt + ((sl ^ (row & 7)) << 3);
      GLD16(Ablk + g, Aw + (size_t)s * 8);
    }
    {
      int s = tid + half * 512;
      int row = s >> 3, sl = s & 7;
      size_t g = (size_t)row * KDIM + kt + ((sl ^ (row & 7)) << 3);
      GLD16(Bqb + g, Bqw + (size_t)s * 8);
      GLD16(Bgb + g, Bgw + (size_t)s * 8);
    }
  };

  auto kstep = [&](const unsigned short* Ar, const unsigned short* Bqr,
                   const unsigned short* Bgr,
                   unsigned short* Aw, unsigned short* Bqw, unsigned short* Bgw,
                   int ktn, bool pre) {
    const unsigned short* Br = is_g ? Bgr : Bqr;
    short8 bf[4][2];
#pragma unroll
    for (int p = 0; p < 4; ++p) {
      short8 af[2][2];
#pragma unroll
      for (int rp = 0; rp < 2; ++rp)
#pragma unroll
        for (int kk = 0; kk < 2; ++kk) {
          int row  = wr + (2 * p + rp) * 16 + la;
          int slot = kk * 4 + l4;
          af[rp][kk] = *(const short8*)(Ar + row * BK + ((slot ^ (row & 7)) << 3));
        }
      if (p == 0) {
#pragma unroll
        for (int j = 0; j < 4; ++j)
#pragma unroll
          for (int kk = 0; kk < 2; ++kk) {
            int row  = wc + j * 16 + la;
            int slot = kk * 4 + l4;
            bf[j][kk] = *(const short8*)(Br + row * BK + ((slot ^ (row & 7)) << 3));
          }
      }
      if (p == 0 && pre) stage_half(Aw, Bqw, Bgw, ktn, 0);
      if (p == 1 && pre) stage_half(Aw, Bqw, Bgw, ktn, 1);
      __builtin_amdgcn_s_barrier();
      __builtin_amdgcn_s_setprio(1);
#pragma unroll
      for (int rp = 0; rp < 2; ++rp)
#pragma unroll
        for (int j = 0; j < 4; ++j)
#pragma unroll
          for (int kk = 0; kk < 2; ++kk)
            acc[2*p+rp][j] = __builtin_amdgcn_mfma_f32_16x16x32_bf16(
                af[rp][kk], bf[j][kk], acc[2*p+rp][j], 0, 0, 0);
      __builtin_amdgcn_s_setprio(0);
      if (p == 3) asm volatile("s_waitcnt vmcnt(0)" ::: "memory");
      __builtin_amdgcn_s_barrier();
    }
  };

  stage_half(As0, Bq0, Bg0, 0, 0);
  stage_half(As0, Bq0, Bg0, 0, 1);
  asm volatile("s_waitcnt vmcnt(0)" ::: "memory");
  __builtin_amdgcn_s_barrier();

  for (int st2 = 0; st2 < NSTEP; st2 += 2) {
    kstep(As0, Bq0, Bg0, As1, Bq1, Bg1, (st2 + 1) * BK, true);
    kstep(As1, Bq1, Bg1, As0, Bq0, Bg0, (st2 + 2) * BK, st2 + 2 < NSTEP);
  }

  // ---- fused finalize ----
  const int b  = bm >> 4;
  const int ro = l4 * 4;
  const int co = la;
  const int hl = wc >> 6;              // head_local (0/1): wave spans one head

  if (!is_g) {
    float kvv[4], ksv[4];
#pragma unroll
    for (int j = 0; j < 4; j++) {
      int col = bn * BN + wc + j * 16 + co;
      kvv[j] = kvsum[(size_t)b * D_MODEL + col];
      ksv[j] = ksum [(size_t)b * D_MODEL + col];
    }
#pragma unroll
    for (int mi = 0; mi < 8; mi++)
#pragma unroll
      for (int r = 0; r < 4; r++) {
        float s = 0.f, z = 0.f;
#pragma unroll
        for (int j = 0; j < 4; j++) {
          float qq = phi_f(acc[mi][j][r]);
          s += qq * kvv[j]; z += qq * ksv[j];
        }
#pragma unroll
        for (int m = 1; m < 16; m <<= 1) {
          s += __shfl_xor(s, m, 64);
          z += __shfl_xor(z, m, 64);
        }
        if (co == 0) o_lds[hl * BM + wr + mi * 16 + ro + r] = s / (z + EPSV);
      }
  }
  __syncthreads();
  if (is_g) {
    float bgv[4];
#pragma unroll
    for (int j = 0; j < 4; j++) bgv[j] = bg[bn * BN + wc + j * 16 + co];
#pragma unroll
    for (int mi = 0; mi < 8; mi++)
#pragma unroll
      for (int r = 0; r < 4; r++) {
        int rowl = wr + mi * 16 + ro + r;
        int grow = bm * BM + rowl;
        float ov = o_lds[hl * BM + rowl];
#pragma unroll
        for (int j = 0; j < 4; j++) {
          int gcol = bn * BN + wc + j * 16 + co;
          float gt = 1.f / (1.f + __expf(-(acc[mi][j][r] + bgv[j])));
          float xv = x[(size_t)grow * D_MODEL + gcol];
          out[(size_t)grow * D_MODEL + gcol] = gt * ov + (1.f - gt) * xv;
        }
      }
  }
}

extern "C" void kernel_launch(void* const* d_in, const int* in_sizes, int n_in,
                              void* d_out, int out_size, void* d_ws, size_t ws_size,
                              hipStream_t stream) {
  (void)in_sizes; (void)n_in; (void)out_size; (void)ws_size;
  const float* x  = (const float*)d_in[0];
  const float* Wq = (const float*)d_in[1];
  const float* Wk = (const float*)d_in[2];
  const float* Wv = (const float*)d_in[3];
  /* d_in[4] = Wo — unused by the reference */
  const float* Wg = (const float*)d_in[5];
  const float* bg = (const float*)d_in[6];
  float* out = (float*)d_out;

  char* ws = (char*)d_ws;
  const size_t xel = (size_t)MROWS * D_MODEL;
  const size_t wel = (size_t)NDIM * KDIM;
  unsigned short* xbf = (unsigned short*)ws; ws += xel * 2;
  unsigned short* wqb = (unsigned short*)ws; ws += wel * 2;
  unsigned short* wkb = (unsigned short*)ws; ws += wel * 2;
  unsigned short* wvb = (unsigned short*)ws; ws += wel * 2;
  unsigned short* wgb = (unsigned short*)ws; ws += wel * 2;
  float* ksum  = (float*)ws; ws += (size_t)BATCH * D_MODEL * 4;  // contiguous
  float* kvsum = (float*)ws; ws += (size_t)BATCH * D_MODEL * 4;

  // 1) fused converts + zero
  const long total4 = (long)NX4 + 4L * NW4 + NZ4;
  prep_kernel<<<(int)((total4 + 255) / 256), 256, 0, stream>>>(
      x, Wq, Wk, Wv, Wg, xbf, wqb, wkb, wvb, wgb, ksum);

  // 2) phase 1: k/v with fused reduction (512 blocks = 8 bn x 64 bm)
  gemm_kv_kernel<<<512, 512, 0, stream>>>(xbf, wkb, wvb, ksum, kvsum);

  // 3) phase 2: q/g with fused finalize
  gemm_qg_kernel<<<512, 512, 0, stream>>>(xbf, wqb, wgb, x, bg, ksum, kvsum, out);
}